// Round 1
// baseline (180.063 us; speedup 1.0000x reference)
//
#include <hip/hip_runtime.h>

#define S_DIM 4096
#define H_DIM 16
#define D_DIM 64
#define N_BLK 64          // S / 64 query blocks
#define PITCH 72          // bf16 elems per LDS row (64 + 8 pad -> 2-way max conflicts)
#define NEG_INF_F (-1e30f)

typedef __attribute__((ext_vector_type(4))) float f32x4;
typedef __attribute__((ext_vector_type(8))) short s16x8;
typedef __attribute__((ext_vector_type(4))) short s16x4;

// fp32 -> bf16 RTNE, branchless (inputs are never NaN here)
__device__ __forceinline__ short f2bf(float f) {
    unsigned int u = __builtin_bit_cast(unsigned int, f);
    unsigned int r = (u + 0x7fffu + ((u >> 16) & 1u)) >> 16;
    return (short)r;
}

// Each 256-thread block = 4 waves; wave w owns query-block n = n0 + w.
// Key-block loop j = n0-2 .. n0+5 (8 stages); wave active when |j - n| <= 2.
// mfma_f32_16x16x32_bf16 layouts (HW-verified per guide):
//   C/D: col = lane&15, row = (lane>>4)*4 + reg
//   A:   m = lane&15,   k = (lane>>4)*8 + j
//   B:   n = lane&15,   k = (lane>>4)*8 + j
__global__ __launch_bounds__(256) void bsattn_kernel(
    const float* __restrict__ qg, const float* __restrict__ kg,
    const float* __restrict__ vg, float* __restrict__ outg)
{
    __shared__ short lds_k [N_BLK * PITCH];      // K tile, bf16 [key][d]
    __shared__ short lds_vt[D_DIM * PITCH];      // V tile transposed, bf16 [d][key]
    __shared__ short lds_p [4 * 64 * PITCH];     // per-wave P buffer [qrow][key]

    const int tid  = threadIdx.x;
    const int w    = tid >> 6;
    const int lane = tid & 63;
    const int quad = lane >> 4;
    const int l16  = lane & 15;

    const int b  = blockIdx.z;
    const int h  = blockIdx.y;
    const int n0 = blockIdx.x << 2;
    const int n  = n0 + w;                       // this wave's query block

    // ---- Q fragments: pre-scaled by 1/sqrt(64)=0.125 (exact), bf16, kept in regs ----
    s16x8 aq[4][2];
#pragma unroll
    for (int rt = 0; rt < 4; ++rt) {
        const size_t qrow = ((size_t)(b * S_DIM + n * 64 + rt * 16 + l16) * H_DIM + h) * D_DIM;
#pragma unroll
        for (int c = 0; c < 2; ++c) {
            const float4* qp = reinterpret_cast<const float4*>(qg + qrow + c * 32 + quad * 8);
            float4 f0 = qp[0];
            float4 f1 = qp[1];
            s16x8 a;
            a[0] = f2bf(f0.x * 0.125f); a[1] = f2bf(f0.y * 0.125f);
            a[2] = f2bf(f0.z * 0.125f); a[3] = f2bf(f0.w * 0.125f);
            a[4] = f2bf(f1.x * 0.125f); a[5] = f2bf(f1.y * 0.125f);
            a[6] = f2bf(f1.z * 0.125f); a[7] = f2bf(f1.w * 0.125f);
            aq[rt][c] = a;
        }
    }

    f32x4 o[4][4];                 // O accumulators: [row-tile][d-tile], C layout
    float m_run[4][4], l_run[4][4];
#pragma unroll
    for (int rt = 0; rt < 4; ++rt) {
#pragma unroll
        for (int t = 0; t < 4; ++t) o[rt][t] = (f32x4){0.f, 0.f, 0.f, 0.f};
#pragma unroll
        for (int r = 0; r < 4; ++r) { m_run[rt][r] = NEG_INF_F; l_run[rt][r] = 0.f; }
    }

    // staging assignment: thread -> (row, 16-float segment)
    const int tr = tid >> 2;                 // 0..63
    const int d0 = (tid & 3) << 4;           // 0,16,32,48

    short* const myp = lds_p + w * (64 * PITCH);

    for (int ji = 0; ji < 8; ++ji) {
        const int j = n0 - 2 + ji;           // key block index
        __syncthreads();                     // previous stage fully consumed
        if (j >= 0 && j < N_BLK) {
            const size_t src = ((size_t)(b * S_DIM + j * 64 + tr) * H_DIM + h) * D_DIM + d0;
            const float4* kp = reinterpret_cast<const float4*>(kg + src);
            const float4* vp = reinterpret_cast<const float4*>(vg + src);
            float4 k0 = kp[0], k1 = kp[1], k2 = kp[2], k3 = kp[3];
            float4 v0 = vp[0], v1 = vp[1], v2 = vp[2], v3 = vp[3];
            short* kd = lds_k + tr * PITCH + d0;
            s16x4 w0 = {f2bf(k0.x), f2bf(k0.y), f2bf(k0.z), f2bf(k0.w)};
            s16x4 w1 = {f2bf(k1.x), f2bf(k1.y), f2bf(k1.z), f2bf(k1.w)};
            s16x4 w2 = {f2bf(k2.x), f2bf(k2.y), f2bf(k2.z), f2bf(k2.w)};
            s16x4 w3 = {f2bf(k3.x), f2bf(k3.y), f2bf(k3.z), f2bf(k3.w)};
            *reinterpret_cast<s16x4*>(kd)      = w0;
            *reinterpret_cast<s16x4*>(kd + 4)  = w1;
            *reinterpret_cast<s16x4*>(kd + 8)  = w2;
            *reinterpret_cast<s16x4*>(kd + 12) = w3;
            float vf[16] = {v0.x, v0.y, v0.z, v0.w, v1.x, v1.y, v1.z, v1.w,
                            v2.x, v2.y, v2.z, v2.w, v3.x, v3.y, v3.z, v3.w};
#pragma unroll
            for (int i = 0; i < 16; ++i)
                lds_vt[(d0 + i) * PITCH + tr] = f2bf(vf[i]);
        }
        __syncthreads();                     // tile visible to all waves

        if (j < 0 || j >= N_BLK) continue;
        const int rel = j - n;
        if (rel < -2 || rel > 2) continue;   // wave-uniform branch

        // ---- scores + online softmax, one 16-row tile at a time ----
#pragma unroll
        for (int rt = 0; rt < 4; ++rt) {
            f32x4 s[4];
#pragma unroll
            for (int t = 0; t < 4; ++t) {
                const short* kb = lds_k + (t * 16 + l16) * PITCH + quad * 8;
                s16x8 b0 = *reinterpret_cast<const s16x8*>(kb);
                s16x8 b1 = *reinterpret_cast<const s16x8*>(kb + 32);
                f32x4 acc = {0.f, 0.f, 0.f, 0.f};
                acc = __builtin_amdgcn_mfma_f32_16x16x32_bf16(aq[rt][0], b0, acc, 0, 0, 0);
                acc = __builtin_amdgcn_mfma_f32_16x16x32_bf16(aq[rt][1], b1, acc, 0, 0, 0);
                s[t] = acc;
            }
            float mnew[4], alpha[4];
#pragma unroll
            for (int r = 0; r < 4; ++r) {
                float mx = fmaxf(fmaxf(s[0][r], s[1][r]), fmaxf(s[2][r], s[3][r]));
                mx = fmaxf(mx, __shfl_xor(mx, 1, 16));
                mx = fmaxf(mx, __shfl_xor(mx, 2, 16));
                mx = fmaxf(mx, __shfl_xor(mx, 4, 16));
                mx = fmaxf(mx, __shfl_xor(mx, 8, 16));
                const float mn = fmaxf(m_run[rt][r], mx);
                alpha[r] = __expf(m_run[rt][r] - mn);
                m_run[rt][r] = mn;
                mnew[r] = mn;
            }
#pragma unroll
            for (int t = 0; t < 4; ++t)
#pragma unroll
                for (int r = 0; r < 4; ++r) s[t][r] = __expf(s[t][r] - mnew[r]);
#pragma unroll
            for (int r = 0; r < 4; ++r) {
                float rs = s[0][r] + s[1][r] + s[2][r] + s[3][r];
                rs += __shfl_xor(rs, 1, 16);
                rs += __shfl_xor(rs, 2, 16);
                rs += __shfl_xor(rs, 4, 16);
                rs += __shfl_xor(rs, 8, 16);
                l_run[rt][r] = l_run[rt][r] * alpha[r] + rs;
#pragma unroll
                for (int t = 0; t < 4; ++t) o[rt][t][r] *= alpha[r];
            }
            // P (C layout) -> per-wave LDS, bf16
#pragma unroll
            for (int t = 0; t < 4; ++t)
#pragma unroll
                for (int r = 0; r < 4; ++r)
                    myp[(rt * 16 + quad * 4 + r) * PITCH + t * 16 + l16] = f2bf(s[t][r]);
        }

        // cross-lane LDS transpose within wave: drain writes before A-frag reads
        asm volatile("s_waitcnt lgkmcnt(0)" ::: "memory");

        // ---- PV: O += P * V ----
#pragma unroll
        for (int rt = 0; rt < 4; ++rt) {
            const short* pr = myp + (rt * 16 + l16) * PITCH + quad * 8;
            s16x8 pa0 = *reinterpret_cast<const s16x8*>(pr);
            s16x8 pa1 = *reinterpret_cast<const s16x8*>(pr + 32);
#pragma unroll
            for (int t = 0; t < 4; ++t) {
                const short* vb = lds_vt + (t * 16 + l16) * PITCH + quad * 8;
                s16x8 b0 = *reinterpret_cast<const s16x8*>(vb);
                s16x8 b1 = *reinterpret_cast<const s16x8*>(vb + 32);
                o[rt][t] = __builtin_amdgcn_mfma_f32_16x16x32_bf16(pa0, b0, o[rt][t], 0, 0, 0);
                o[rt][t] = __builtin_amdgcn_mfma_f32_16x16x32_bf16(pa1, b1, o[rt][t], 0, 0, 0);
            }
        }
    }

    // ---- epilogue: normalize and store ----
#pragma unroll
    for (int rt = 0; rt < 4; ++rt) {
#pragma unroll
        for (int r = 0; r < 4; ++r) {
            const float inv = 1.0f / l_run[rt][r];
            float* op = outg +
                ((size_t)(b * S_DIM + n * 64 + rt * 16 + quad * 4 + r) * H_DIM + h) * D_DIM + l16;
#pragma unroll
            for (int t = 0; t < 4; ++t)
                op[t * 16] = o[rt][t][r] * inv;
        }
    }
}

extern "C" void kernel_launch(void* const* d_in, const int* in_sizes, int n_in,
                              void* d_out, int out_size, void* d_ws, size_t ws_size,
                              hipStream_t stream) {
    const float* q = (const float*)d_in[0];
    const float* k = (const float*)d_in[1];
    const float* v = (const float*)d_in[2];
    float* out = (float*)d_out;
    const int B = in_sizes[0] / (S_DIM * H_DIM * D_DIM);   // = 2
    dim3 grid(N_BLK / 4, H_DIM, B);
    dim3 block(256);
    hipLaunchKernelGGL(bsattn_kernel, grid, block, 0, stream, q, k, v, out);
}

// Round 2
// 161.806 us; speedup vs baseline: 1.1128x; 1.1128x over previous
//
#include <hip/hip_runtime.h>

#define S_DIM 4096
#define H_DIM 16
#define D_DIM 64
#define N_BLK 64          // S / 64 query blocks
#define PITCH 72          // bf16 elems per LDS row (64 + 8 pad)
#define NEG_INF_F (-1e30f)
#define QSCALE 0.125f     // 1/sqrt(64), exact

typedef __attribute__((ext_vector_type(4))) float f32x4;
typedef __attribute__((ext_vector_type(8))) short s16x8;
typedef __attribute__((ext_vector_type(4))) short s16x4;
typedef __attribute__((ext_vector_type(4))) unsigned int u32x4;
typedef __attribute__((ext_vector_type(2))) unsigned int u32x2;

__device__ __forceinline__ unsigned int fbits(float f) {
    return __builtin_bit_cast(unsigned int, f);
}
// pack two floats -> two bf16 (round-half-up; inputs never NaN here). lo=a, hi=b
__device__ __forceinline__ unsigned int pkbf(float a, float b) {
    return __builtin_amdgcn_perm(fbits(b) + 0x8000u, fbits(a) + 0x8000u, 0x07060302u);
}
__device__ __forceinline__ short f2bf1(float f) {
    return (short)((fbits(f) + 0x8000u) >> 16);
}

// Block = 4 waves x 32 queries = 2 query-blocks (n0, n0+1). Stages j = n0-2 .. n0+3.
// S^T trick: QK^T computed as K(A) x Q(B) -> lane holds S[query=l16][key=kt*16+4*quad+r].
// With the PV contraction index permuted as kappa(k=8*quad+j) = 32h+4*quad+j (j<4),
// 32h+16+4*quad+(j-4) (j>=4), each lane's own exp'ed values form the PV A-fragment
// directly -- no cross-lane P transpose. V B-frags read with the same permutation
// (two ds_read_b64 per half from vt[d][key]).
__global__ __launch_bounds__(256, 4) void bsattn_kernel(
    const float* __restrict__ qg, const float* __restrict__ kg,
    const float* __restrict__ vg, float* __restrict__ outg)
{
    __shared__ short lds_k [N_BLK * PITCH];   // K tile bf16 [key][d]
    __shared__ short lds_vt[D_DIM * PITCH];   // V tile bf16 transposed [d][key]

    const int tid  = threadIdx.x;
    const int w    = tid >> 6;
    const int lane = tid & 63;
    const int quad = lane >> 4;
    const int l16  = lane & 15;

    const int b  = blockIdx.z;
    const int h  = blockIdx.y;
    const int n0 = blockIdx.x << 1;
    const int n  = n0 + (w >> 1);                 // this wave's query block
    const int qrow0 = n * 64 + (w & 1) * 32;      // first of this wave's 32 queries

    // ---- Q fragments (B-operand): bq[qt][half], pre-scaled, bf16 ----
    s16x8 bq[2][2];
#pragma unroll
    for (int qt = 0; qt < 2; ++qt) {
        const size_t qrow = ((size_t)(b * S_DIM + qrow0 + qt * 16 + l16) * H_DIM + h) * D_DIM;
#pragma unroll
        for (int hh = 0; hh < 2; ++hh) {
            const float4* qp = reinterpret_cast<const float4*>(qg + qrow + hh * 32 + quad * 8);
            float4 f0 = qp[0];
            float4 f1 = qp[1];
            u32x4 u;
            u.x = pkbf(f0.x * QSCALE, f0.y * QSCALE);
            u.y = pkbf(f0.z * QSCALE, f0.w * QSCALE);
            u.z = pkbf(f1.x * QSCALE, f1.y * QSCALE);
            u.w = pkbf(f1.z * QSCALE, f1.w * QSCALE);
            bq[qt][hh] = __builtin_bit_cast(s16x8, u);
        }
    }

    f32x4 o[2][4];                   // O accum [qt][dt], C layout (row=query, col=d)
    float m_run[2], l_run[2];
#pragma unroll
    for (int qt = 0; qt < 2; ++qt) {
        m_run[qt] = NEG_INF_F; l_run[qt] = 0.f;
#pragma unroll
        for (int dt = 0; dt < 4; ++dt) o[qt][dt] = (f32x4){0.f, 0.f, 0.f, 0.f};
    }

    const int tr = tid >> 2;                 // staging row 0..63
    const int d0 = (tid & 3) << 4;           // staging d-segment

    for (int ji = 0; ji < 6; ++ji) {
        const int j = n0 - 2 + ji;           // key block index
        __syncthreads();                     // previous tile fully consumed
        if (j >= 0 && j < N_BLK) {
            const size_t src = ((size_t)(b * S_DIM + j * 64 + tr) * H_DIM + h) * D_DIM + d0;
            const float4* kp = reinterpret_cast<const float4*>(kg + src);
            const float4* vp = reinterpret_cast<const float4*>(vg + src);
            float4 k0 = kp[0], k1 = kp[1], k2 = kp[2], k3 = kp[3];
            float4 v0 = vp[0], v1 = vp[1], v2 = vp[2], v3 = vp[3];
            short* kd = lds_k + tr * PITCH + d0;
            u32x2 ka = {pkbf(k0.x, k0.y), pkbf(k0.z, k0.w)};
            u32x2 kb = {pkbf(k1.x, k1.y), pkbf(k1.z, k1.w)};
            u32x2 kc = {pkbf(k2.x, k2.y), pkbf(k2.z, k2.w)};
            u32x2 ke = {pkbf(k3.x, k3.y), pkbf(k3.z, k3.w)};
            *reinterpret_cast<u32x2*>(kd)      = ka;
            *reinterpret_cast<u32x2*>(kd + 4)  = kb;
            *reinterpret_cast<u32x2*>(kd + 8)  = kc;
            *reinterpret_cast<u32x2*>(kd + 12) = ke;
            float vf[16] = {v0.x, v0.y, v0.z, v0.w, v1.x, v1.y, v1.z, v1.w,
                            v2.x, v2.y, v2.z, v2.w, v3.x, v3.y, v3.z, v3.w};
#pragma unroll
            for (int i = 0; i < 16; ++i)
                lds_vt[(d0 + i) * PITCH + tr] = f2bf1(vf[i]);
        }
        __syncthreads();                     // tile visible to all waves

        if (j < 0 || j >= N_BLK) continue;
        const int rel = j - n;
        if (rel < -2 || rel > 2) continue;   // wave-uniform branch

        // ---- S^T = K x Q^T : sa[qt][kt], lane: query l16, keys kt*16+4*quad+r ----
        f32x4 sa[2][4];
#pragma unroll
        for (int kt = 0; kt < 4; ++kt) {
            const short* kbp = lds_k + (kt * 16 + l16) * PITCH + quad * 8;
            s16x8 kf0 = *reinterpret_cast<const s16x8*>(kbp);
            s16x8 kf1 = *reinterpret_cast<const s16x8*>(kbp + 32);
            f32x4 z = {0.f, 0.f, 0.f, 0.f};
            f32x4 a0 = __builtin_amdgcn_mfma_f32_16x16x32_bf16(kf0, bq[0][0], z, 0, 0, 0);
            sa[0][kt] = __builtin_amdgcn_mfma_f32_16x16x32_bf16(kf1, bq[0][1], a0, 0, 0, 0);
            f32x4 a1 = __builtin_amdgcn_mfma_f32_16x16x32_bf16(kf0, bq[1][0], z, 0, 0, 0);
            sa[1][kt] = __builtin_amdgcn_mfma_f32_16x16x32_bf16(kf1, bq[1][1], a1, 0, 0, 0);
        }

        // ---- online softmax per qt; P stays in registers ----
        s16x8 pa[2][2];
#pragma unroll
        for (int qt = 0; qt < 2; ++qt) {
            float mx = NEG_INF_F;
#pragma unroll
            for (int kt = 0; kt < 4; ++kt)
#pragma unroll
                for (int r = 0; r < 4; ++r) mx = fmaxf(mx, sa[qt][kt][r]);
            mx = fmaxf(mx, __shfl_xor(mx, 16));
            mx = fmaxf(mx, __shfl_xor(mx, 32));
            const float mn = fmaxf(m_run[qt], mx);
            const float alpha = __expf(m_run[qt] - mn);
            m_run[qt] = mn;

            float rs = 0.f;
            unsigned int pk[4][2];
#pragma unroll
            for (int kt = 0; kt < 4; ++kt) {
                float e0 = __expf(sa[qt][kt][0] - mn);
                float e1 = __expf(sa[qt][kt][1] - mn);
                float e2 = __expf(sa[qt][kt][2] - mn);
                float e3 = __expf(sa[qt][kt][3] - mn);
                rs += (e0 + e1) + (e2 + e3);
                pk[kt][0] = pkbf(e0, e1);
                pk[kt][1] = pkbf(e2, e3);
            }
            rs += __shfl_xor(rs, 16);
            rs += __shfl_xor(rs, 32);
            l_run[qt] = l_run[qt] * alpha + rs;

            float ab[4];
#pragma unroll
            for (int r = 0; r < 4; ++r)
                ab[r] = __shfl(alpha, (lane & 48) + quad * 4 + r);
#pragma unroll
            for (int dt = 0; dt < 4; ++dt)
#pragma unroll
                for (int r = 0; r < 4; ++r) o[qt][dt][r] *= ab[r];

            pa[qt][0] = __builtin_bit_cast(s16x8, (u32x4){pk[0][0], pk[0][1], pk[1][0], pk[1][1]});
            pa[qt][1] = __builtin_bit_cast(s16x8, (u32x4){pk[2][0], pk[2][1], pk[3][0], pk[3][1]});
        }

        // ---- PV: O += P x V, key order permuted to match pa ----
#pragma unroll
        for (int dt = 0; dt < 4; ++dt) {
            const short* vb = lds_vt + (dt * 16 + l16) * PITCH + quad * 4;
            s16x4 v00 = *reinterpret_cast<const s16x4*>(vb);        // keys 4q..4q+3
            s16x4 v01 = *reinterpret_cast<const s16x4*>(vb + 16);   // keys 16+4q..
            s16x4 v10 = *reinterpret_cast<const s16x4*>(vb + 32);   // keys 32+4q..
            s16x4 v11 = *reinterpret_cast<const s16x4*>(vb + 48);   // keys 48+4q..
            s16x8 vf0 = {v00[0], v00[1], v00[2], v00[3], v01[0], v01[1], v01[2], v01[3]};
            s16x8 vf1 = {v10[0], v10[1], v10[2], v10[3], v11[0], v11[1], v11[2], v11[3]};
#pragma unroll
            for (int qt = 0; qt < 2; ++qt) {
                o[qt][dt] = __builtin_amdgcn_mfma_f32_16x16x32_bf16(pa[qt][0], vf0, o[qt][dt], 0, 0, 0);
                o[qt][dt] = __builtin_amdgcn_mfma_f32_16x16x32_bf16(pa[qt][1], vf1, o[qt][dt], 0, 0, 0);
            }
        }
    }

    // ---- epilogue: broadcast l to row layout, normalize, store ----
#pragma unroll
    for (int qt = 0; qt < 2; ++qt) {
#pragma unroll
        for (int r = 0; r < 4; ++r) {
            const float lb = __shfl(l_run[qt], (lane & 48) + quad * 4 + r);
            const float inv = 1.0f / lb;
            const int row = qrow0 + qt * 16 + quad * 4 + r;
            float* op = outg + ((size_t)(b * S_DIM + row) * H_DIM + h) * D_DIM + l16;
#pragma unroll
            for (int dt = 0; dt < 4; ++dt)
                op[dt * 16] = o[qt][dt][r] * inv;
        }
    }
}

extern "C" void kernel_launch(void* const* d_in, const int* in_sizes, int n_in,
                              void* d_out, int out_size, void* d_ws, size_t ws_size,
                              hipStream_t stream) {
    const float* q = (const float*)d_in[0];
    const float* k = (const float*)d_in[1];
    const float* v = (const float*)d_in[2];
    float* out = (float*)d_out;
    const int B = in_sizes[0] / (S_DIM * H_DIM * D_DIM);   // = 2
    dim3 grid(N_BLK / 2, H_DIM, B);
    dim3 block(256);
    hipLaunchKernelGGL(bsattn_kernel, grid, block, 0, stream, q, k, v, out);
}